// Round 6
// baseline (331.012 us; speedup 1.0000x reference)
//
#include <hip/hip_runtime.h>

typedef unsigned short ushort_t;
typedef unsigned int   uint32;
typedef __attribute__((ext_vector_type(8)))  short short8;    // 8 x bf16 (4 VGPRs)
typedef __attribute__((ext_vector_type(4)))  float floatx4;
typedef __attribute__((ext_vector_type(16))) float floatx16;  // 32x32 MFMA accumulator

#define IN_F   4096
#define OUT_F  8192
#define M_TOT  512

__device__ __forceinline__ ushort_t f2bf(float f) {
    uint32 u = __builtin_bit_cast(uint32, f);
    u += 0x7FFFu + ((u >> 16) & 1u);    // RNE
    return (ushort_t)(u >> 16);
}
__device__ __forceinline__ uint32 pack2bf(float a, float b) {
    return (uint32)f2bf(a) | ((uint32)f2bf(b) << 16);
}

// ---------------------------------------------------------------------------
// Kernel 0: x fp32 -> bf16, MFMA-blocked layout XB[mt][kt][32][16]:
// ushort offset = ((mt*256 + kt)*32 + (m&31))*16 + (k&15),  mt=m>>5, kt=k>>4.
// Each 32x32x16 A-fragment is one contiguous 1 KB segment -> per-lane 16B
// fully-coalesced loads in the fused GEMM.
__global__ void cvt_x_kernel(const float* __restrict__ x, ushort_t* __restrict__ xb) {
    const int g  = blockIdx.x * 256 + threadIdx.x;   // 262144 threads total
    const int r  = g >> 9;                           // row 0..511
    const int k0 = (g & 511) * 8;                    // k octet
    float4 v0 = *(const float4*)(x + (size_t)r * IN_F + k0);
    float4 v1 = *(const float4*)(x + (size_t)r * IN_F + k0 + 4);
    short8 s;
    s[0] = (short)f2bf(v0.x); s[1] = (short)f2bf(v0.y);
    s[2] = (short)f2bf(v0.z); s[3] = (short)f2bf(v0.w);
    s[4] = (short)f2bf(v1.x); s[5] = (short)f2bf(v1.y);
    s[6] = (short)f2bf(v1.z); s[7] = (short)f2bf(v1.w);
    const int mt = r >> 5;
    const int kt = k0 >> 4;
    ushort_t* dst = xb + ((size_t)(mt * 256 + kt) * 32 + (r & 31)) * 16 + (k0 & 15);
    *(short8*)dst = s;
}

// ---------------------------------------------------------------------------
// Fused dequant + GEMM + scale, round-6 latency surgery.
//
// Round-5 counters: 135us, MfmaUtil 10%, VALUBusy 6.6%, 10.1k cyc/iter vs
// ~3k of pipe demand -> still latency-serialized.  The per-iter serial chain:
// (a) a-frag loads issued and consumed in the SAME iteration (L2/L3 latency
// exposed; index stream thrashes the 4MB XCD L2 so a-loads often go to L3);
// (b) dequant LDS lookups queued BEFORE b-frag reads -> in-order lgkm queue
// delays every MFMA start.
//
// Fixes: (1) register double-buffer a-frags (aA/aB, static-indexed), issue
// t+1's a-loads at top of iter t; (2) hoist idx-load issue to body top (3
// tiles in flight); (3) dequant moved AFTER the MFMA cluster; (4) setprio(1)
// around MFMAs (T5 - role diversity now exists); (5) prologue barriers
// lgkm-only too.  Barrier stays raw s_barrier + lgkmcnt(0)-only drain (T3/T4,
// validated round 5); vmcnt never drains in the main loop.
#define LGKM_BARRIER()                                          \
    asm volatile("s_waitcnt lgkmcnt(0)" ::: "memory");          \
    __builtin_amdgcn_sched_barrier(0);                          \
    __builtin_amdgcn_s_barrier();

__global__ __launch_bounds__(1024, 4)
void fused_kernel(const ushort_t* __restrict__ xb, const int* __restrict__ base_idx,
                  const int* __restrict__ fine_idx, const float* __restrict__ lut,
                  const float* __restrict__ scale, float* __restrict__ out)
{
    __shared__ ushort_t sh_lut[65536];        // 128 KB bf16 LUT
    __shared__ ushort_t sh_w[2][32 * 128];    // 2 x 8 KB w-tiles (BK=128)

    const int tid  = threadIdx.x;
    const int nblk = blockIdx.x;              // col-block: cols [32*nblk, +32)

    // Stage LUT fp32 -> bf16 (each thread 64 entries).
    for (int i = tid * 4; i < 65536; i += 4096) {
        float4 v = *(const float4*)(lut + i);
        *(uint32*)&sh_lut[i]     = pack2bf(v.x, v.y);
        *(uint32*)&sh_lut[i + 2] = pack2bf(v.z, v.w);
    }

    // Dequant role: thread -> (col = tid>>5, k-quad kq within 128-wide tile).
    const int colr = tid >> 5;                // 0..31
    const int kq   = (tid & 31) * 4;          // 0,4,..,124
    const int4* bp = (const int4*)(base_idx + (size_t)(nblk * 32 + colr) * IN_F + kq);
    const int4* fp = (const int4*)(fine_idx + (size_t)(nblk * 32 + colr) * IN_F + kq);
    // tile t lives at bp[t*32] (128 ints = 32 int4 per col per tile)

    // Swizzled write offset: elems (colr, kq..kq+3), chunk = kq>>3 (4 bits),
    // slot = chunk ^ (colr&7) on low 3 bits; kq&7 in {0,4} -> one aligned b64.
    const int woff = colr * 128 + (((kq >> 3) ^ (colr & 7)) << 3) + (kq & 7);

    const int lane = tid & 63;
    const int wave = tid >> 6;                // 0..15 = m-tile index
    const int l31  = lane & 31;
    const int lhi  = lane >> 5;
    const int rx8  = l31 & 7;                 // read-side swizzle key

    // Blocked A base: XB tile (mt=wave, kt) = 512 ushorts; lane slot l31*16+lhi*8.
    const ushort_t* abase = xb + (size_t)wave * 256 * 512 + l31 * 16 + lhi * 8;

    // Prologue index loads.
    int4 ib0 = bp[0];                         // tile 0
    int4 if0 = fp[0];
    int4 Ib  = bp[32];                        // tile 1
    int4 If  = fp[32];
    int4 Nb  = bp[64];                        // tile 2
    int4 Nf  = fp[64];

    // Preload a-frags for t=0 (bank A).
    short8 aA[8], aB[8];
#pragma unroll
    for (int i = 0; i < 8; ++i)
        aA[i] = *(const short8*)(abase + (size_t)i * 512);

    LGKM_BARRIER();                           // LUT ready (LDS-only drain)

    {   // dequant tile 0 into sh_w[0]
        uint32 w0 = (uint32)sh_lut[(ib0.x << 8) + if0.x]
                  | ((uint32)sh_lut[(ib0.y << 8) + if0.y] << 16);
        uint32 w1 = (uint32)sh_lut[(ib0.z << 8) + if0.z]
                  | ((uint32)sh_lut[(ib0.w << 8) + if0.w] << 16);
        uint2 wv; wv.x = w0; wv.y = w1;
        *(uint2*)&sh_w[0][woff] = wv;
    }

    LGKM_BARRIER();                           // tile 0 visible

    floatx16 acc = {0.f,0.f,0.f,0.f,0.f,0.f,0.f,0.f,0.f,0.f,0.f,0.f,0.f,0.f,0.f,0.f};

    // Body: (1) issue idx loads tile T+3, (2) issue a-prefetch for T+1 into
    // bank AY, (3) b-reads + MFMAs on bank AX (setprio-wrapped), (4) dequant
    // tile T+1 (lookups run in barrier shadow, after b-reads in lgkm queue),
    // (5) lgkm-only barrier.
#define GBODY(T, AX, AY)                                                       \
    {                                                                          \
        const int cur = (T) & 1;                                               \
        const int tl  = ((T) + 3 < 32) ? (T) + 3 : 31;                         \
        int4 Tb = bp[tl * 32];                                                 \
        int4 Tf = fp[tl * 32];                                                 \
        if ((T) + 1 < 32) {                                                    \
            _Pragma("unroll")                                                  \
            for (int i = 0; i < 8; ++i)                                        \
                AY[i] = *(const short8*)(abase + (size_t)(((T) + 1) * 8 + i) * 512); \
        }                                                                      \
        const ushort_t* wb = sh_w[cur];                                        \
        __builtin_amdgcn_s_setprio(1);                                         \
        _Pragma("unroll")                                                      \
        for (int i = 0; i < 8; ++i) {                                          \
            short8 bfr = *(const short8*)&wb[l31 * 128 + (((2 * i + lhi) ^ rx8) << 3)]; \
            acc = __builtin_amdgcn_mfma_f32_32x32x16_bf16(AX[i], bfr, acc, 0, 0, 0);    \
        }                                                                      \
        __builtin_amdgcn_s_setprio(0);                                         \
        if ((T) < 31) {                                                        \
            uint32 w0 = (uint32)sh_lut[(Ib.x << 8) + If.x]                     \
                      | ((uint32)sh_lut[(Ib.y << 8) + If.y] << 16);            \
            uint32 w1 = (uint32)sh_lut[(Ib.z << 8) + If.z]                     \
                      | ((uint32)sh_lut[(Ib.w << 8) + If.w] << 16);            \
            uint2 wv; wv.x = w0; wv.y = w1;                                    \
            *(uint2*)&sh_w[cur ^ 1][woff] = wv;                                \
            Ib = Nb; If = Nf; Nb = Tb; Nf = Tf;                                \
        }                                                                      \
        LGKM_BARRIER();                                                        \
    }

    for (int t = 0; t < 32; t += 2) {
        GBODY(t, aA, aB)
        GBODY(t + 1, aB, aA)
    }
#undef GBODY

    // Epilogue: out[row][col] = acc * scale[col]  (32x32 C/D mapping:
    // col=l31, row=(reg&3)+8*(reg>>2)+4*lhi — verified in earlier rounds).
    const float sc = scale[nblk * 32 + l31];
    float* op = out + (size_t)(nblk * 32 + l31);
    const int rbase = wave * 32 + 4 * lhi;
#pragma unroll
    for (int reg = 0; reg < 16; ++reg) {
        const int row = rbase + (reg & 3) + 8 * (reg >> 2);
        op[(size_t)row * OUT_F] = acc[reg] * sc;
    }
}

// ---------------------------------------------------------------------------
// Fallback: fused kernel for tiny workspace (x read as fp32).
#define NB  32
#define FBK 128
#define WS  136
#define NITER (IN_F / FBK)
__global__ __launch_bounds__(1024, 4)
void ghost_kernel(const float* __restrict__ xf,
                  const int* __restrict__ base_idx, const int* __restrict__ fine_idx,
                  const float* __restrict__ scale, const float* __restrict__ lut,
                  float* __restrict__ out)
{
    __shared__ ushort_t sh_lut[65536];
    __shared__ ushort_t sh_w[2][NB * WS];
    const int tid = threadIdx.x;
    const int n0  = blockIdx.x * NB;
    for (int i = tid * 4; i < 65536; i += 1024 * 4) {
        float4 v = *(const float4*)(lut + i);
        sh_lut[i + 0] = f2bf(v.x); sh_lut[i + 1] = f2bf(v.y);
        sh_lut[i + 2] = f2bf(v.z); sh_lut[i + 3] = f2bf(v.w);
    }
    const int sn  = tid >> 5;
    const int skq = (tid & 31) * 4;
    const int* bp = base_idx + (size_t)(n0 + sn) * IN_F + skq;
    const int* fp = fine_idx + (size_t)(n0 + sn) * IN_F + skq;
    __syncthreads();
    int4 pb = *(const int4*)(bp);
    int4 pf = *(const int4*)(fp);
    {
        uint32 w0 = (uint32)sh_lut[(pb.x << 8) + pf.x] | ((uint32)sh_lut[(pb.y << 8) + pf.y] << 16);
        uint32 w1 = (uint32)sh_lut[(pb.z << 8) + pf.z] | ((uint32)sh_lut[(pb.w << 8) + pf.w] << 16);
        uint2 wv; wv.x = w0; wv.y = w1;
        *(uint2*)&sh_w[0][sn * WS + skq] = wv;
    }
    pb = *(const int4*)(bp + FBK);
    pf = *(const int4*)(fp + FBK);
    __syncthreads();
    const int lane = tid & 63;
    const int wave = tid >> 6;
    const int l16  = lane & 15;
    const int quad = lane >> 4;
    floatx4 acc[2][2];
    const floatx4 zero = {0.f, 0.f, 0.f, 0.f};
    acc[0][0] = zero; acc[0][1] = zero; acc[1][0] = zero; acc[1][1] = zero;
    const int mrow = wave * 32 + l16;
    const float* xrowf = xf + (size_t)mrow * IN_F + quad * 8;
    for (int t = 0; t < NITER; ++t) {
        const int k0 = t * FBK;
        {
            uint32 w0 = (uint32)sh_lut[(pb.x << 8) + pf.x] | ((uint32)sh_lut[(pb.y << 8) + pf.y] << 16);
            uint32 w1 = (uint32)sh_lut[(pb.z << 8) + pf.z] | ((uint32)sh_lut[(pb.w << 8) + pf.w] << 16);
            uint2 wv; wv.x = w0; wv.y = w1;
            *(uint2*)&sh_w[(t + 1) & 1][sn * WS + skq] = wv;
        }
        {
            const int kk = (t + 2 < NITER ? t + 2 : NITER - 1) * FBK;
            pb = *(const int4*)(bp + kk);
            pf = *(const int4*)(fp + kk);
        }
        const ushort_t* wb = sh_w[t & 1];
#pragma unroll
        for (int ks = 0; ks < 4; ++ks) {
            const int kk = k0 + ks * 32;
            short8 b0 = *(const short8*)&wb[l16        * WS + ks * 32 + quad * 8];
            short8 b1 = *(const short8*)&wb[(16 + l16) * WS + ks * 32 + quad * 8];
            short8 a0, a1;
            const float* p0 = xrowf + kk;
            const float* p1 = xrowf + (size_t)16 * IN_F + kk;
            float4 u0 = *(const float4*)p0, u1 = *(const float4*)(p0 + 4);
            float4 v0 = *(const float4*)p1, v1 = *(const float4*)(p1 + 4);
            a0[0] = (short)f2bf(u0.x); a0[1] = (short)f2bf(u0.y);
            a0[2] = (short)f2bf(u0.z); a0[3] = (short)f2bf(u0.w);
            a0[4] = (short)f2bf(u1.x); a0[5] = (short)f2bf(u1.y);
            a0[6] = (short)f2bf(u1.z); a0[7] = (short)f2bf(u1.w);
            a1[0] = (short)f2bf(v0.x); a1[1] = (short)f2bf(v0.y);
            a1[2] = (short)f2bf(v0.z); a1[3] = (short)f2bf(v0.w);
            a1[4] = (short)f2bf(v1.x); a1[5] = (short)f2bf(v1.y);
            a1[6] = (short)f2bf(v1.z); a1[7] = (short)f2bf(v1.w);
            acc[0][0] = __builtin_amdgcn_mfma_f32_16x16x32_bf16(a0, b0, acc[0][0], 0, 0, 0);
            acc[0][1] = __builtin_amdgcn_mfma_f32_16x16x32_bf16(a0, b1, acc[0][1], 0, 0, 0);
            acc[1][0] = __builtin_amdgcn_mfma_f32_16x16x32_bf16(a1, b0, acc[1][0], 0, 0, 0);
            acc[1][1] = __builtin_amdgcn_mfma_f32_16x16x32_bf16(a1, b1, acc[1][1], 0, 0, 0);
        }
        __syncthreads();
    }
#pragma unroll
    for (int nf = 0; nf < 2; ++nf) {
        const int col = n0 + nf * 16 + l16;
        const float sc = scale[col];
#pragma unroll
        for (int f = 0; f < 2; ++f) {
            const int r0 = wave * 32 + f * 16 + quad * 4;
#pragma unroll
            for (int r = 0; r < 4; ++r) {
                out[(size_t)(r0 + r) * OUT_F + col] = acc[f][nf][r] * sc;
            }
        }
    }
}

// ---------------------------------------------------------------------------
extern "C" void kernel_launch(void* const* d_in, const int* in_sizes, int n_in,
                              void* d_out, int out_size, void* d_ws, size_t ws_size,
                              hipStream_t stream) {
    const float* x      = (const float*)d_in[0];
    const int*   bidx   = (const int*)d_in[1];
    const int*   fidx   = (const int*)d_in[2];
    const float* scale  = (const float*)d_in[3];
    const float* lut    = (const float*)d_in[4];
    float*       out    = (float*)d_out;

    const size_t xb_bytes = (size_t)M_TOT * IN_F * sizeof(ushort_t);   // 4 MB

    if (ws_size >= xb_bytes) {
        ushort_t* xbuf = (ushort_t*)d_ws;
        cvt_x_kernel<<<1024, 256, 0, stream>>>(x, xbuf);
        fused_kernel<<<256, 1024, 0, stream>>>(xbuf, bidx, fidx, lut, scale, out);
    } else {
        ghost_kernel<<<OUT_F / NB, 1024, 0, stream>>>(x, bidx, fidx, scale, lut, out);
    }
}

// Round 7
// 328.532 us; speedup vs baseline: 1.0075x; 1.0075x over previous
//
#include <hip/hip_runtime.h>

typedef unsigned short ushort_t;
typedef unsigned int   uint32;
typedef __attribute__((ext_vector_type(8)))  short short8;    // 8 x bf16 (4 VGPRs)
typedef __attribute__((ext_vector_type(4)))  float floatx4;
typedef __attribute__((ext_vector_type(16))) float floatx16;  // 32x32 MFMA accumulator
typedef __attribute__((ext_vector_type(4)))  int   intx4;     // NT-loadable int4
typedef __attribute__((ext_vector_type(4)))  float fltx4;     // NT-loadable float4

#define IN_F   4096
#define OUT_F  8192
#define M_TOT  512

__device__ __forceinline__ ushort_t f2bf(float f) {
    uint32 u = __builtin_bit_cast(uint32, f);
    u += 0x7FFFu + ((u >> 16) & 1u);    // RNE
    return (ushort_t)(u >> 16);
}
__device__ __forceinline__ uint32 pack2bf(float a, float b) {
    return (uint32)f2bf(a) | ((uint32)f2bf(b) << 16);
}

// ---------------------------------------------------------------------------
// Kernel 0: x fp32 -> bf16, MFMA-blocked layout XB[mt][kt][32][16]:
// ushort offset = ((mt*256 + kt)*32 + (m&31))*16 + (k&15),  mt=m>>5, kt=k>>4.
// Each 32x32x16 A-fragment is one contiguous 1 KB segment -> per-lane 16B
// fully-coalesced loads in the fused GEMM.
__global__ void cvt_x_kernel(const float* __restrict__ x, ushort_t* __restrict__ xb) {
    const int g  = blockIdx.x * 256 + threadIdx.x;   // 262144 threads total
    const int r  = g >> 9;                           // row 0..511
    const int k0 = (g & 511) * 8;                    // k octet
    float4 v0 = *(const float4*)(x + (size_t)r * IN_F + k0);
    float4 v1 = *(const float4*)(x + (size_t)r * IN_F + k0 + 4);
    short8 s;
    s[0] = (short)f2bf(v0.x); s[1] = (short)f2bf(v0.y);
    s[2] = (short)f2bf(v0.z); s[3] = (short)f2bf(v0.w);
    s[4] = (short)f2bf(v1.x); s[5] = (short)f2bf(v1.y);
    s[6] = (short)f2bf(v1.z); s[7] = (short)f2bf(v1.w);
    const int mt = r >> 5;
    const int kt = k0 >> 4;
    ushort_t* dst = xb + ((size_t)(mt * 256 + kt) * 32 + (r & 31)) * 16 + (k0 & 15);
    *(short8*)dst = s;
}

// ---------------------------------------------------------------------------
// Fused dequant + GEMM + scale, round-7: non-temporal index stream.
//
// Round-6 counters: 128us, MfmaUtil 10.4%, VALUBusy 6.5%, ~8.9k cyc/iter vs
// ~2.3k LDS floor.  Revised accounting: every block re-reads the whole 4MB
// xb -> 1 GB of A-traffic (invisible in FETCH_SIZE, which shows only the
// 150MB idx stream).  xb (4MB) == one XCD L2; the 268MB idx stream flowing
// through the same L2 evicts xb, pushing a-loads to L3 (~5.4k cyc/iter
// aggregate-BW-bound).  Fix: mark idx loads (single-use) and LUT staging
// loads NON-TEMPORAL (evict-first) so xb stays L2-resident.  Round-2's
// attempt failed on HIP struct int4 — __builtin_nontemporal_load accepts
// ext_vector types (intx4/fltx4).
//
// Schedule (validated rounds 5-6, kept): raw s_barrier + lgkmcnt(0)-only
// drain (vmcnt never drains in-loop); BK=128, 32 iters; reg-double-buffered
// a-frags issued one iter ahead; dequant after MFMA cluster; setprio around
// MFMAs.
#define LGKM_BARRIER()                                          \
    asm volatile("s_waitcnt lgkmcnt(0)" ::: "memory");          \
    __builtin_amdgcn_sched_barrier(0);                          \
    __builtin_amdgcn_s_barrier();

__global__ __launch_bounds__(1024, 4)
void fused_kernel(const ushort_t* __restrict__ xb, const int* __restrict__ base_idx,
                  const int* __restrict__ fine_idx, const float* __restrict__ lut,
                  const float* __restrict__ scale, float* __restrict__ out)
{
    __shared__ ushort_t sh_lut[65536];        // 128 KB bf16 LUT
    __shared__ ushort_t sh_w[2][32 * 128];    // 2 x 8 KB w-tiles (BK=128)

    const int tid  = threadIdx.x;
    const int nblk = blockIdx.x;              // col-block: cols [32*nblk, +32)

    // Stage LUT fp32 -> bf16 (NT: 64MB aggregate burst, read once per block).
    for (int i = tid * 4; i < 65536; i += 4096) {
        fltx4 v = __builtin_nontemporal_load((const fltx4*)(lut + i));
        *(uint32*)&sh_lut[i]     = pack2bf(v.x, v.y);
        *(uint32*)&sh_lut[i + 2] = pack2bf(v.z, v.w);
    }

    // Dequant role: thread -> (col = tid>>5, k-quad kq within 128-wide tile).
    const int colr = tid >> 5;                // 0..31
    const int kq   = (tid & 31) * 4;          // 0,4,..,124
    const intx4* bp = (const intx4*)(base_idx + (size_t)(nblk * 32 + colr) * IN_F + kq);
    const intx4* fp = (const intx4*)(fine_idx + (size_t)(nblk * 32 + colr) * IN_F + kq);
    // tile t lives at bp[t*32] (128 ints = 32 int4 per col per tile)

    // Swizzled write offset: elems (colr, kq..kq+3), chunk = kq>>3 (4 bits),
    // slot = chunk ^ (colr&7) on low 3 bits; kq&7 in {0,4} -> one aligned b64.
    const int woff = colr * 128 + (((kq >> 3) ^ (colr & 7)) << 3) + (kq & 7);

    const int lane = tid & 63;
    const int wave = tid >> 6;                // 0..15 = m-tile index
    const int l31  = lane & 31;
    const int lhi  = lane >> 5;
    const int rx8  = l31 & 7;                 // read-side swizzle key

    // Blocked A base: XB tile (mt=wave, kt) = 512 ushorts; lane slot l31*16+lhi*8.
    const ushort_t* abase = xb + (size_t)wave * 256 * 512 + l31 * 16 + lhi * 8;

    // Prologue index loads (non-temporal: single-use stream, keep xb in L2).
    intx4 ib0 = __builtin_nontemporal_load(bp);        // tile 0
    intx4 if0 = __builtin_nontemporal_load(fp);
    intx4 Ib  = __builtin_nontemporal_load(bp + 32);   // tile 1
    intx4 If  = __builtin_nontemporal_load(fp + 32);
    intx4 Nb  = __builtin_nontemporal_load(bp + 64);   // tile 2
    intx4 Nf  = __builtin_nontemporal_load(fp + 64);

    // Preload a-frags for t=0 (bank A).
    short8 aA[8], aB[8];
#pragma unroll
    for (int i = 0; i < 8; ++i)
        aA[i] = *(const short8*)(abase + (size_t)i * 512);

    LGKM_BARRIER();                           // LUT ready (LDS-only drain)

    {   // dequant tile 0 into sh_w[0]
        uint32 w0 = (uint32)sh_lut[(ib0.x << 8) + if0.x]
                  | ((uint32)sh_lut[(ib0.y << 8) + if0.y] << 16);
        uint32 w1 = (uint32)sh_lut[(ib0.z << 8) + if0.z]
                  | ((uint32)sh_lut[(ib0.w << 8) + if0.w] << 16);
        uint2 wv; wv.x = w0; wv.y = w1;
        *(uint2*)&sh_w[0][woff] = wv;
    }

    LGKM_BARRIER();                           // tile 0 visible

    floatx16 acc = {0.f,0.f,0.f,0.f,0.f,0.f,0.f,0.f,0.f,0.f,0.f,0.f,0.f,0.f,0.f,0.f};

    // Body: (1) issue NT idx loads tile T+3, (2) issue a-prefetch for T+1
    // into bank AY, (3) b-reads + MFMAs on bank AX (setprio-wrapped),
    // (4) dequant tile T+1 (lookups after b-reads in lgkm queue), (5) barrier.
#define GBODY(T, AX, AY)                                                       \
    {                                                                          \
        const int cur = (T) & 1;                                               \
        const int tl  = ((T) + 3 < 32) ? (T) + 3 : 31;                         \
        intx4 Tb = __builtin_nontemporal_load(bp + tl * 32);                   \
        intx4 Tf = __builtin_nontemporal_load(fp + tl * 32);                   \
        if ((T) + 1 < 32) {                                                    \
            _Pragma("unroll")                                                  \
            for (int i = 0; i < 8; ++i)                                        \
                AY[i] = *(const short8*)(abase + (size_t)(((T) + 1) * 8 + i) * 512); \
        }                                                                      \
        const ushort_t* wb = sh_w[cur];                                        \
        __builtin_amdgcn_s_setprio(1);                                         \
        _Pragma("unroll")                                                      \
        for (int i = 0; i < 8; ++i) {                                          \
            short8 bfr = *(const short8*)&wb[l31 * 128 + (((2 * i + lhi) ^ rx8) << 3)]; \
            acc = __builtin_amdgcn_mfma_f32_32x32x16_bf16(AX[i], bfr, acc, 0, 0, 0);    \
        }                                                                      \
        __builtin_amdgcn_s_setprio(0);                                         \
        if ((T) < 31) {                                                        \
            uint32 w0 = (uint32)sh_lut[(Ib.x << 8) + If.x]                     \
                      | ((uint32)sh_lut[(Ib.y << 8) + If.y] << 16);            \
            uint32 w1 = (uint32)sh_lut[(Ib.z << 8) + If.z]                     \
                      | ((uint32)sh_lut[(Ib.w << 8) + If.w] << 16);            \
            uint2 wv; wv.x = w0; wv.y = w1;                                    \
            *(uint2*)&sh_w[cur ^ 1][woff] = wv;                                \
            Ib = Nb; If = Nf; Nb = Tb; Nf = Tf;                                \
        }                                                                      \
        LGKM_BARRIER();                                                        \
    }

    for (int t = 0; t < 32; t += 2) {
        GBODY(t, aA, aB)
        GBODY(t + 1, aB, aA)
    }
#undef GBODY

    // Epilogue: out[row][col] = acc * scale[col]  (32x32 C/D mapping:
    // col=l31, row=(reg&3)+8*(reg>>2)+4*lhi — verified in earlier rounds).
    const float sc = scale[nblk * 32 + l31];
    float* op = out + (size_t)(nblk * 32 + l31);
    const int rbase = wave * 32 + 4 * lhi;
#pragma unroll
    for (int reg = 0; reg < 16; ++reg) {
        const int row = rbase + (reg & 3) + 8 * (reg >> 2);
        op[(size_t)row * OUT_F] = acc[reg] * sc;
    }
}

// ---------------------------------------------------------------------------
// Fallback: fused kernel for tiny workspace (x read as fp32).
#define NB  32
#define FBK 128
#define WS  136
#define NITER (IN_F / FBK)
__global__ __launch_bounds__(1024, 4)
void ghost_kernel(const float* __restrict__ xf,
                  const int* __restrict__ base_idx, const int* __restrict__ fine_idx,
                  const float* __restrict__ scale, const float* __restrict__ lut,
                  float* __restrict__ out)
{
    __shared__ ushort_t sh_lut[65536];
    __shared__ ushort_t sh_w[2][NB * WS];
    const int tid = threadIdx.x;
    const int n0  = blockIdx.x * NB;
    for (int i = tid * 4; i < 65536; i += 1024 * 4) {
        float4 v = *(const float4*)(lut + i);
        sh_lut[i + 0] = f2bf(v.x); sh_lut[i + 1] = f2bf(v.y);
        sh_lut[i + 2] = f2bf(v.z); sh_lut[i + 3] = f2bf(v.w);
    }
    const int sn  = tid >> 5;
    const int skq = (tid & 31) * 4;
    const int* bp = base_idx + (size_t)(n0 + sn) * IN_F + skq;
    const int* fp = fine_idx + (size_t)(n0 + sn) * IN_F + skq;
    __syncthreads();
    int4 pb = *(const int4*)(bp);
    int4 pf = *(const int4*)(fp);
    {
        uint32 w0 = (uint32)sh_lut[(pb.x << 8) + pf.x] | ((uint32)sh_lut[(pb.y << 8) + pf.y] << 16);
        uint32 w1 = (uint32)sh_lut[(pb.z << 8) + pf.z] | ((uint32)sh_lut[(pb.w << 8) + pf.w] << 16);
        uint2 wv; wv.x = w0; wv.y = w1;
        *(uint2*)&sh_w[0][sn * WS + skq] = wv;
    }
    pb = *(const int4*)(bp + FBK);
    pf = *(const int4*)(fp + FBK);
    __syncthreads();
    const int lane = tid & 63;
    const int wave = tid >> 6;
    const int l16  = lane & 15;
    const int quad = lane >> 4;
    floatx4 acc[2][2];
    const floatx4 zero = {0.f, 0.f, 0.f, 0.f};
    acc[0][0] = zero; acc[0][1] = zero; acc[1][0] = zero; acc[1][1] = zero;
    const int mrow = wave * 32 + l16;
    const float* xrowf = xf + (size_t)mrow * IN_F + quad * 8;
    for (int t = 0; t < NITER; ++t) {
        const int k0 = t * FBK;
        {
            uint32 w0 = (uint32)sh_lut[(pb.x << 8) + pf.x] | ((uint32)sh_lut[(pb.y << 8) + pf.y] << 16);
            uint32 w1 = (uint32)sh_lut[(pb.z << 8) + pf.z] | ((uint32)sh_lut[(pb.w << 8) + pf.w] << 16);
            uint2 wv; wv.x = w0; wv.y = w1;
            *(uint2*)&sh_w[(t + 1) & 1][sn * WS + skq] = wv;
        }
        {
            const int kk = (t + 2 < NITER ? t + 2 : NITER - 1) * FBK;
            pb = *(const int4*)(bp + kk);
            pf = *(const int4*)(fp + kk);
        }
        const ushort_t* wb = sh_w[t & 1];
#pragma unroll
        for (int ks = 0; ks < 4; ++ks) {
            const int kk = k0 + ks * 32;
            short8 b0 = *(const short8*)&wb[l16        * WS + ks * 32 + quad * 8];
            short8 b1 = *(const short8*)&wb[(16 + l16) * WS + ks * 32 + quad * 8];
            short8 a0, a1;
            const float* p0 = xrowf + kk;
            const float* p1 = xrowf + (size_t)16 * IN_F + kk;
            float4 u0 = *(const float4*)p0, u1 = *(const float4*)(p0 + 4);
            float4 v0 = *(const float4*)p1, v1 = *(const float4*)(p1 + 4);
            a0[0] = (short)f2bf(u0.x); a0[1] = (short)f2bf(u0.y);
            a0[2] = (short)f2bf(u0.z); a0[3] = (short)f2bf(u0.w);
            a0[4] = (short)f2bf(u1.x); a0[5] = (short)f2bf(u1.y);
            a0[6] = (short)f2bf(u1.z); a0[7] = (short)f2bf(u1.w);
            a1[0] = (short)f2bf(v0.x); a1[1] = (short)f2bf(v0.y);
            a1[2] = (short)f2bf(v0.z); a1[3] = (short)f2bf(v0.w);
            a1[4] = (short)f2bf(v1.x); a1[5] = (short)f2bf(v1.y);
            a1[6] = (short)f2bf(v1.z); a1[7] = (short)f2bf(v1.w);
            acc[0][0] = __builtin_amdgcn_mfma_f32_16x16x32_bf16(a0, b0, acc[0][0], 0, 0, 0);
            acc[0][1] = __builtin_amdgcn_mfma_f32_16x16x32_bf16(a0, b1, acc[0][1], 0, 0, 0);
            acc[1][0] = __builtin_amdgcn_mfma_f32_16x16x32_bf16(a1, b0, acc[1][0], 0, 0, 0);
            acc[1][1] = __builtin_amdgcn_mfma_f32_16x16x32_bf16(a1, b1, acc[1][1], 0, 0, 0);
        }
        __syncthreads();
    }
#pragma unroll
    for (int nf = 0; nf < 2; ++nf) {
        const int col = n0 + nf * 16 + l16;
        const float sc = scale[col];
#pragma unroll
        for (int f = 0; f < 2; ++f) {
            const int r0 = wave * 32 + f * 16 + quad * 4;
#pragma unroll
            for (int r = 0; r < 4; ++r) {
                out[(size_t)(r0 + r) * OUT_F + col] = acc[f][nf][r] * sc;
            }
        }
    }
}

// ---------------------------------------------------------------------------
extern "C" void kernel_launch(void* const* d_in, const int* in_sizes, int n_in,
                              void* d_out, int out_size, void* d_ws, size_t ws_size,
                              hipStream_t stream) {
    const float* x      = (const float*)d_in[0];
    const int*   bidx   = (const int*)d_in[1];
    const int*   fidx   = (const int*)d_in[2];
    const float* scale  = (const float*)d_in[3];
    const float* lut    = (const float*)d_in[4];
    float*       out    = (float*)d_out;

    const size_t xb_bytes = (size_t)M_TOT * IN_F * sizeof(ushort_t);   // 4 MB

    if (ws_size >= xb_bytes) {
        ushort_t* xbuf = (ushort_t*)d_ws;
        cvt_x_kernel<<<1024, 256, 0, stream>>>(x, xbuf);
        fused_kernel<<<256, 1024, 0, stream>>>(xbuf, bidx, fidx, lut, scale, out);
    } else {
        ghost_kernel<<<OUT_F / NB, 1024, 0, stream>>>(x, bidx, fidx, scale, lut, out);
    }
}

// Round 8
// 327.274 us; speedup vs baseline: 1.0114x; 1.0038x over previous
//
#include <hip/hip_runtime.h>

typedef unsigned short ushort_t;
typedef unsigned int   uint32;
typedef __attribute__((ext_vector_type(8)))  short short8;    // 8 x bf16 (4 VGPRs)
typedef __attribute__((ext_vector_type(4)))  float floatx4;
typedef __attribute__((ext_vector_type(16))) float floatx16;  // 32x32 MFMA accumulator
typedef __attribute__((ext_vector_type(4)))  int   intx4;     // NT-loadable int4
typedef __attribute__((ext_vector_type(4)))  float fltx4;     // NT-loadable float4

#define IN_F   4096
#define OUT_F  8192
#define M_TOT  512

__device__ __forceinline__ ushort_t f2bf(float f) {
    uint32 u = __builtin_bit_cast(uint32, f);
    u += 0x7FFFu + ((u >> 16) & 1u);    // RNE
    return (ushort_t)(u >> 16);
}
__device__ __forceinline__ uint32 pack2bf(float a, float b) {
    return (uint32)f2bf(a) | ((uint32)f2bf(b) << 16);
}

// ---------------------------------------------------------------------------
// Kernel 0: x fp32 -> bf16, MFMA-blocked layout XB[mt][kt][32][16]:
// ushort offset = ((mt*256 + kt)*32 + (m&31))*16 + (k&15),  mt=m>>5, kt=k>>4.
// Each 32x32x16 A-fragment is one contiguous 1 KB segment -> per-lane 16B
// fully-coalesced loads in the fused GEMM.
__global__ void cvt_x_kernel(const float* __restrict__ x, ushort_t* __restrict__ xb) {
    const int g  = blockIdx.x * 256 + threadIdx.x;   // 262144 threads total
    const int r  = g >> 9;                           // row 0..511
    const int k0 = (g & 511) * 8;                    // k octet
    float4 v0 = *(const float4*)(x + (size_t)r * IN_F + k0);
    float4 v1 = *(const float4*)(x + (size_t)r * IN_F + k0 + 4);
    short8 s;
    s[0] = (short)f2bf(v0.x); s[1] = (short)f2bf(v0.y);
    s[2] = (short)f2bf(v0.z); s[3] = (short)f2bf(v0.w);
    s[4] = (short)f2bf(v1.x); s[5] = (short)f2bf(v1.y);
    s[6] = (short)f2bf(v1.z); s[7] = (short)f2bf(v1.w);
    const int mt = r >> 5;
    const int kt = k0 >> 4;
    ushort_t* dst = xb + ((size_t)(mt * 256 + kt) * 32 + (r & 31)) * 16 + (k0 & 15);
    *(short8*)dst = s;
}

// ---------------------------------------------------------------------------
// Fused dequant + GEMM + scale, round-8: triple-buffered w-tiles, ZERO
// waitcnt in the main loop.
//
// Round-7: 109us, MfmaUtil 12.4%, ~8.2k cyc/iter vs ~2k pipe demand.  The
// remaining serial cost is the per-iter lgkmcnt(0) drain: with 2 buffers the
// tile written at iter T is read at T+1, so the 4 random LUT lookups (~120cy
// + ~836 cyc/iter measured conflicts) + ds_write must DRAIN inside every
// barrier, and the barrier propagates the slowest wave's conflict draw.
//
// Fix: 3 w-tile buffers (152KB LDS total).  Iter T reads buf[T%3], dequants
// tile T+2 into buf[(T+2)%3] -> the write has one full iteration of slack.
// lgkm (DS) ops complete IN ORDER, so the compiler's own b-frag waits at
// iter T+1 force write_T completion before the T+1-end barrier, which orders
// it before any read at T+2.  The loop barrier is sched_barrier(0)+s_barrier
// with NO waitcnt: lookup latency + conflict stragglers move off the critical
// path (LDS analog of T4's "never drain vmcnt to 0").
//
// Kept from rounds 5-7 (each verified): BK=128/32 iters, reg-double-buffered
// a-frags one iter ahead, dequant after MFMA cluster, setprio around MFMAs,
// NT index/LUT loads (keeps xb L2-resident; R7 +15%).
__global__ __launch_bounds__(1024, 4)
void fused_kernel(const ushort_t* __restrict__ xb, const int* __restrict__ base_idx,
                  const int* __restrict__ fine_idx, const float* __restrict__ lut,
                  const float* __restrict__ scale, float* __restrict__ out)
{
    __shared__ ushort_t sh_lut[65536];        // 128 KB bf16 LUT
    __shared__ ushort_t sh_w[3][32 * 128];    // 3 x 8 KB w-tiles (BK=128)

    const int tid  = threadIdx.x;
    const int nblk = blockIdx.x;              // col-block: cols [32*nblk, +32)

    // Stage LUT fp32 -> bf16 (NT: read once per block).
    for (int i = tid * 4; i < 65536; i += 4096) {
        fltx4 v = __builtin_nontemporal_load((const fltx4*)(lut + i));
        *(uint32*)&sh_lut[i]     = pack2bf(v.x, v.y);
        *(uint32*)&sh_lut[i + 2] = pack2bf(v.z, v.w);
    }

    // Dequant role: thread -> (col = tid>>5, k-quad kq within 128-wide tile).
    const int colr = tid >> 5;                // 0..31
    const int kq   = (tid & 31) * 4;          // 0,4,..,124
    const intx4* bp = (const intx4*)(base_idx + (size_t)(nblk * 32 + colr) * IN_F + kq);
    const intx4* fp = (const intx4*)(fine_idx + (size_t)(nblk * 32 + colr) * IN_F + kq);
    // tile t lives at bp[t*32] (128 ints = 32 int4 per col per tile)

    // Swizzled write offset: elems (colr, kq..kq+3), chunk = kq>>3 (4 bits),
    // slot = chunk ^ (colr&7) on low 3 bits; kq&7 in {0,4} -> one aligned b64.
    const int woff = colr * 128 + (((kq >> 3) ^ (colr & 7)) << 3) + (kq & 7);

    const int lane = tid & 63;
    const int wave = tid >> 6;                // 0..15 = m-tile index
    const int l31  = lane & 31;
    const int lhi  = lane >> 5;
    const int rx8  = l31 & 7;                 // read-side swizzle key

    // Blocked A base: XB tile (mt=wave, kt) = 512 ushorts; lane slot l31*16+lhi*8.
    const ushort_t* abase = xb + (size_t)wave * 256 * 512 + l31 * 16 + lhi * 8;

    // Prologue index loads (NT, single-use stream).
    intx4 i0b = __builtin_nontemporal_load(bp);        // tile 0
    intx4 i0f = __builtin_nontemporal_load(fp);
    intx4 i1b = __builtin_nontemporal_load(bp + 32);   // tile 1
    intx4 i1f = __builtin_nontemporal_load(fp + 32);
    intx4 Ib  = __builtin_nontemporal_load(bp + 64);   // tile 2 (first loop dequant)
    intx4 If  = __builtin_nontemporal_load(fp + 64);
    intx4 Nb  = __builtin_nontemporal_load(bp + 96);   // tile 3
    intx4 Nf  = __builtin_nontemporal_load(fp + 96);
    intx4 Pb = {0, 0, 0, 0}, Pf = {0, 0, 0, 0};        // tile T+4 in-flight

    // Preload a-frags for t=0 (bank A).
    short8 aA[8], aB[8];
#pragma unroll
    for (int i = 0; i < 8; ++i)
        aA[i] = *(const short8*)(abase + (size_t)i * 512);

    // LUT ready (full drain, once).
    asm volatile("s_waitcnt lgkmcnt(0)" ::: "memory");
    __builtin_amdgcn_sched_barrier(0);
    __builtin_amdgcn_s_barrier();

    {   // dequant tiles 0,1 into buf0,buf1
        uint32 w0 = (uint32)sh_lut[(i0b.x << 8) + i0f.x]
                  | ((uint32)sh_lut[(i0b.y << 8) + i0f.y] << 16);
        uint32 w1 = (uint32)sh_lut[(i0b.z << 8) + i0f.z]
                  | ((uint32)sh_lut[(i0b.w << 8) + i0f.w] << 16);
        uint2 wv; wv.x = w0; wv.y = w1;
        *(uint2*)&sh_w[0][woff] = wv;
        w0 = (uint32)sh_lut[(i1b.x << 8) + i1f.x]
           | ((uint32)sh_lut[(i1b.y << 8) + i1f.y] << 16);
        w1 = (uint32)sh_lut[(i1b.z << 8) + i1f.z]
           | ((uint32)sh_lut[(i1b.w << 8) + i1f.w] << 16);
        wv.x = w0; wv.y = w1;
        *(uint2*)&sh_w[1][woff] = wv;
    }

    // bufs 0,1 visible (full drain, once).
    asm volatile("s_waitcnt lgkmcnt(0)" ::: "memory");
    __builtin_amdgcn_sched_barrier(0);
    __builtin_amdgcn_s_barrier();

    floatx16 acc = {0.f,0.f,0.f,0.f,0.f,0.f,0.f,0.f,0.f,0.f,0.f,0.f,0.f,0.f,0.f,0.f};

    // Body at iter T (=t+K): (1) issue NT idx loads for tile T+4, (2) a-frag
    // prefetch for T+1 into bank AY, (3) MFMAs on buf[CUR]=buf[T%3] with AX,
    // (4) dequant tile T+2 into buf[WD]=buf[(T+2)%3], (5) raw barrier, NO
    // waitcnt.  CUR/WD/banks are compile-time (6-body unroll, lcm(2,3)).
#define GBODY(K, AX, AY, CUR, WD)                                              \
    {                                                                          \
        const int T = t + (K);                                                 \
        if (T + 4 < 32) {                                                      \
            Pb = __builtin_nontemporal_load(bp + (T + 4) * 32);                \
            Pf = __builtin_nontemporal_load(fp + (T + 4) * 32);                \
        }                                                                      \
        if (T + 1 < 32) {                                                      \
            _Pragma("unroll")                                                  \
            for (int i = 0; i < 8; ++i)                                        \
                AY[i] = *(const short8*)(abase + (size_t)((T + 1) * 8 + i) * 512); \
        }                                                                      \
        const ushort_t* wb = sh_w[CUR];                                        \
        __builtin_amdgcn_s_setprio(1);                                         \
        _Pragma("unroll")                                                      \
        for (int i = 0; i < 8; ++i) {                                          \
            short8 bfr = *(const short8*)&wb[l31 * 128 + (((2 * i + lhi) ^ rx8) << 3)]; \
            acc = __builtin_amdgcn_mfma_f32_32x32x16_bf16(AX[i], bfr, acc, 0, 0, 0);    \
        }                                                                      \
        __builtin_amdgcn_s_setprio(0);                                         \
        if (T + 2 < 32) {                                                      \
            uint32 w0 = (uint32)sh_lut[(Ib.x << 8) + If.x]                     \
                      | ((uint32)sh_lut[(Ib.y << 8) + If.y] << 16);            \
            uint32 w1 = (uint32)sh_lut[(Ib.z << 8) + If.z]                     \
                      | ((uint32)sh_lut[(Ib.w << 8) + If.w] << 16);            \
            uint2 wv; wv.x = w0; wv.y = w1;                                    \
            *(uint2*)&sh_w[WD][woff] = wv;                                     \
            Ib = Nb; If = Nf; Nb = Pb; Nf = Pf;                                \
        }                                                                      \
        __builtin_amdgcn_sched_barrier(0);                                     \
        __builtin_amdgcn_s_barrier();                                          \
    }

    int t = 0;
    for (; t < 30; t += 6) {
        GBODY(0, aA, aB, 0, 2)
        GBODY(1, aB, aA, 1, 0)
        GBODY(2, aA, aB, 2, 1)
        GBODY(3, aB, aA, 0, 2)
        GBODY(4, aA, aB, 1, 0)
        GBODY(5, aB, aA, 2, 1)
    }
    // t == 30 tail (T=30 reads buf0 w/ aA, prefetches aB; T=31 reads buf1).
    GBODY(0, aA, aB, 0, 2)
    GBODY(1, aB, aA, 1, 0)
#undef GBODY

    // Epilogue: out[row][col] = acc * scale[col]  (32x32 C/D mapping:
    // col=l31, row=(reg&3)+8*(reg>>2)+4*lhi — verified in earlier rounds).
    const float sc = scale[nblk * 32 + l31];
    float* op = out + (size_t)(nblk * 32 + l31);
    const int rbase = wave * 32 + 4 * lhi;
#pragma unroll
    for (int reg = 0; reg < 16; ++reg) {
        const int row = rbase + (reg & 3) + 8 * (reg >> 2);
        op[(size_t)row * OUT_F] = acc[reg] * sc;
    }
}

// ---------------------------------------------------------------------------
// Fallback: fused kernel for tiny workspace (x read as fp32).
#define NB  32
#define FBK 128
#define WS  136
#define NITER (IN_F / FBK)
__global__ __launch_bounds__(1024, 4)
void ghost_kernel(const float* __restrict__ xf,
                  const int* __restrict__ base_idx, const int* __restrict__ fine_idx,
                  const float* __restrict__ scale, const float* __restrict__ lut,
                  float* __restrict__ out)
{
    __shared__ ushort_t sh_lut[65536];
    __shared__ ushort_t sh_w[2][NB * WS];
    const int tid = threadIdx.x;
    const int n0  = blockIdx.x * NB;
    for (int i = tid * 4; i < 65536; i += 1024 * 4) {
        float4 v = *(const float4*)(lut + i);
        sh_lut[i + 0] = f2bf(v.x); sh_lut[i + 1] = f2bf(v.y);
        sh_lut[i + 2] = f2bf(v.z); sh_lut[i + 3] = f2bf(v.w);
    }
    const int sn  = tid >> 5;
    const int skq = (tid & 31) * 4;
    const int* bp = base_idx + (size_t)(n0 + sn) * IN_F + skq;
    const int* fp = fine_idx + (size_t)(n0 + sn) * IN_F + skq;
    __syncthreads();
    int4 pb = *(const int4*)(bp);
    int4 pf = *(const int4*)(fp);
    {
        uint32 w0 = (uint32)sh_lut[(pb.x << 8) + pf.x] | ((uint32)sh_lut[(pb.y << 8) + pf.y] << 16);
        uint32 w1 = (uint32)sh_lut[(pb.z << 8) + pf.z] | ((uint32)sh_lut[(pb.w << 8) + pf.w] << 16);
        uint2 wv; wv.x = w0; wv.y = w1;
        *(uint2*)&sh_w[0][sn * WS + skq] = wv;
    }
    pb = *(const int4*)(bp + FBK);
    pf = *(const int4*)(fp + FBK);
    __syncthreads();
    const int lane = tid & 63;
    const int wave = tid >> 6;
    const int l16  = lane & 15;
    const int quad = lane >> 4;
    floatx4 acc[2][2];
    const floatx4 zero = {0.f, 0.f, 0.f, 0.f};
    acc[0][0] = zero; acc[0][1] = zero; acc[1][0] = zero; acc[1][1] = zero;
    const int mrow = wave * 32 + l16;
    const float* xrowf = xf + (size_t)mrow * IN_F + quad * 8;
    for (int t = 0; t < NITER; ++t) {
        const int k0 = t * FBK;
        {
            uint32 w0 = (uint32)sh_lut[(pb.x << 8) + pf.x] | ((uint32)sh_lut[(pb.y << 8) + pf.y] << 16);
            uint32 w1 = (uint32)sh_lut[(pb.z << 8) + pf.z] | ((uint32)sh_lut[(pb.w << 8) + pf.w] << 16);
            uint2 wv; wv.x = w0; wv.y = w1;
            *(uint2*)&sh_w[(t + 1) & 1][sn * WS + skq] = wv;
        }
        {
            const int kk = (t + 2 < NITER ? t + 2 : NITER - 1) * FBK;
            pb = *(const int4*)(bp + kk);
            pf = *(const int4*)(fp + kk);
        }
        const ushort_t* wb = sh_w[t & 1];
#pragma unroll
        for (int ks = 0; ks < 4; ++ks) {
            const int kk = k0 + ks * 32;
            short8 b0 = *(const short8*)&wb[l16        * WS + ks * 32 + quad * 8];
            short8 b1 = *(const short8*)&wb[(16 + l16) * WS + ks * 32 + quad * 8];
            short8 a0, a1;
            const float* p0 = xrowf + kk;
            const float* p1 = xrowf + (size_t)16 * IN_F + kk;
            float4 u0 = *(const float4*)p0, u1 = *(const float4*)(p0 + 4);
            float4 v0 = *(const float4*)p1, v1 = *(const float4*)(p1 + 4);
            a0[0] = (short)f2bf(u0.x); a0[1] = (short)f2bf(u0.y);
            a0[2] = (short)f2bf(u0.z); a0[3] = (short)f2bf(u0.w);
            a0[4] = (short)f2bf(u1.x); a0[5] = (short)f2bf(u1.y);
            a0[6] = (short)f2bf(u1.z); a0[7] = (short)f2bf(u1.w);
            a1[0] = (short)f2bf(v0.x); a1[1] = (short)f2bf(v0.y);
            a1[2] = (short)f2bf(v0.z); a1[3] = (short)f2bf(v0.w);
            a1[4] = (short)f2bf(v1.x); a1[5] = (short)f2bf(v1.y);
            a1[6] = (short)f2bf(v1.z); a1[7] = (short)f2bf(v1.w);
            acc[0][0] = __builtin_amdgcn_mfma_f32_16x16x32_bf16(a0, b0, acc[0][0], 0, 0, 0);
            acc[0][1] = __builtin_amdgcn_mfma_f32_16x16x32_bf16(a0, b1, acc[0][1], 0, 0, 0);
            acc[1][0] = __builtin_amdgcn_mfma_f32_16x16x32_bf16(a1, b0, acc[1][0], 0, 0, 0);
            acc[1][1] = __builtin_amdgcn_mfma_f32_16x16x32_bf16(a1, b1, acc[1][1], 0, 0, 0);
        }
        __syncthreads();
    }
#pragma unroll
    for (int nf = 0; nf < 2; ++nf) {
        const int col = n0 + nf * 16 + l16;
        const float sc = scale[col];
#pragma unroll
        for (int f = 0; f < 2; ++f) {
            const int r0 = wave * 32 + f * 16 + quad * 4;
#pragma unroll
            for (int r = 0; r < 4; ++r) {
                out[(size_t)(r0 + r) * OUT_F + col] = acc[f][nf][r] * sc;
            }
        }
    }
}

// ---------------------------------------------------------------------------
extern "C" void kernel_launch(void* const* d_in, const int* in_sizes, int n_in,
                              void* d_out, int out_size, void* d_ws, size_t ws_size,
                              hipStream_t stream) {
    const float* x      = (const float*)d_in[0];
    const int*   bidx   = (const int*)d_in[1];
    const int*   fidx   = (const int*)d_in[2];
    const float* scale  = (const float*)d_in[3];
    const float* lut    = (const float*)d_in[4];
    float*       out    = (float*)d_out;

    const size_t xb_bytes = (size_t)M_TOT * IN_F * sizeof(ushort_t);   // 4 MB

    if (ws_size >= xb_bytes) {
        ushort_t* xbuf = (ushort_t*)d_ws;
        cvt_x_kernel<<<1024, 256, 0, stream>>>(x, xbuf);
        fused_kernel<<<256, 1024, 0, stream>>>(xbuf, bidx, fidx, lut, scale, out);
    } else {
        ghost_kernel<<<OUT_F / NB, 1024, 0, stream>>>(x, bidx, fidx, scale, lut, out);
    }
}